// Round 20
// baseline (228.021 us; speedup 1.0000x reference)
//
#include <hip/hip_runtime.h>
#include <math.h>

#define G 5000
#define IN 64
#define D 128
#define E 240000
#define EG (E + G)
#define SLOPE 0.2f
#define GD (G * D)
#define CAP 128          // fixed bucket capacity per destination (deg ~ Poisson(48)+1)
#define NB_PG 1250       // pergene blocks (4 genes each)
#define NB_H 240         // bucket blocks (61440 int4 units >= 61250)
#define NB_X 1250        // xlxr blocks (4 genes each)

__device__ __forceinline__ float leaky(float v) { return v >= 0.f ? v : SLOPE * v; }

// ---------------- K_A: pergene (round-2 exact body) + bucket (fixed-cap) ----------------
__global__ __launch_bounds__(256) void k_fuseA(const float* __restrict__ x,
                                               const float* __restrict__ Win,
                                               const float* __restrict__ bin,
                                               float* __restrict__ h,
                                               const int* __restrict__ srcA,
                                               const int* __restrict__ dstA,
                                               int* __restrict__ cnt,
                                               int* __restrict__ ssrc,
                                               float* __restrict__ outz) {
    if (blockIdx.x == 0 && threadIdx.x == 0) *outz = 0.f;   // consumed only by k_final8 (stream-ordered)
    if (blockIdx.x < NB_PG) {
        int g = (blockIdx.x * 256 + threadIdx.x) >> 6;
        int lane = threadIdx.x & 63;
        if (g >= G) return;
        float xv = x[g * IN + lane];
        const float* W = Win + (size_t)g * IN * D + lane * 2;
        float2 acc = *(const float2*)(bin + g * D + lane * 2);
#pragma unroll
        for (int i = 0; i < IN; ++i) {
            float xi = __shfl(xv, i);
            float2 w2 = *(const float2*)(W + (size_t)i * D);
            acc.x = fmaf(xi, w2.x, acc.x);
            acc.y = fmaf(xi, w2.y, acc.y);
        }
        float2 o = { fmaxf(acc.x, 0.f), fmaxf(acc.y, 0.f) };
        *(float2*)(h + g * D + lane * 2) = o;
    } else {
        int base = ((blockIdx.x - NB_PG) * 256 + threadIdx.x) * 4;
        if (base >= EG) return;
        if (base + 4 <= E) {
            int4 s4 = *(const int4*)(srcA + base);
            int4 d4 = *(const int4*)(dstA + base);
            int p;
            p = atomicAdd(&cnt[d4.x], 1); if (p < CAP) ssrc[d4.x * CAP + p] = s4.x;
            p = atomicAdd(&cnt[d4.y], 1); if (p < CAP) ssrc[d4.y * CAP + p] = s4.y;
            p = atomicAdd(&cnt[d4.z], 1); if (p < CAP) ssrc[d4.z * CAP + p] = s4.z;
            p = atomicAdd(&cnt[d4.w], 1); if (p < CAP) ssrc[d4.w * CAP + p] = s4.w;
        } else {
            for (int kk = 0; kk < 4; ++kk) {
                int i = base + kk;
                if (i < EG) {
                    int s, t;
                    if (i < E) { s = srcA[i]; t = dstA[i]; }
                    else { s = i - E; t = s; }
                    int p = atomicAdd(&cnt[t], 1);
                    if (p < CAP) ssrc[t * CAP + p] = s;
                }
            }
        }
    }
}

// ---------------- K_XLXR3: column-per-thread, 4 genes/block (round-16 exact) ----------------
__global__ __launch_bounds__(256) void k_xlxr3(const float* __restrict__ h,
                                               const float* __restrict__ Wl,
                                               const float* __restrict__ bl,
                                               const float* __restrict__ Wr,
                                               const float* __restrict__ br,
                                               float* __restrict__ xl,
                                               float* __restrict__ xr) {
    int g0 = blockIdx.x * 4;
    int tid = threadIdx.x;
    int half = tid >> 7;
    int col = tid & 127;
    const float* W = half ? Wr : Wl;
    const float* bb = half ? br : bl;
    float* o = half ? xr : xl;
    const float* h0p = h + (size_t)(g0 + 0) * D;
    const float* h1p = h + (size_t)(g0 + 1) * D;
    const float* h2p = h + (size_t)(g0 + 2) * D;
    const float* h3p = h + (size_t)(g0 + 3) * D;
    float b = bb[col];
    float acc0 = b, acc1 = b, acc2 = b, acc3 = b;
#pragma unroll 8
    for (int k4 = 0; k4 < 32; ++k4) {
        int k = k4 * 4;
        float4 hv0 = *(const float4*)(h0p + k);
        float4 hv1 = *(const float4*)(h1p + k);
        float4 hv2 = *(const float4*)(h2p + k);
        float4 hv3 = *(const float4*)(h3p + k);
        float w0 = W[(size_t)(k + 0) * D + col];
        float w1 = W[(size_t)(k + 1) * D + col];
        float w2 = W[(size_t)(k + 2) * D + col];
        float w3 = W[(size_t)(k + 3) * D + col];
        acc0 = fmaf(hv0.x, w0, acc0); acc0 = fmaf(hv0.y, w1, acc0);
        acc0 = fmaf(hv0.z, w2, acc0); acc0 = fmaf(hv0.w, w3, acc0);
        acc1 = fmaf(hv1.x, w0, acc1); acc1 = fmaf(hv1.y, w1, acc1);
        acc1 = fmaf(hv1.z, w2, acc1); acc1 = fmaf(hv1.w, w3, acc1);
        acc2 = fmaf(hv2.x, w0, acc2); acc2 = fmaf(hv2.y, w1, acc2);
        acc2 = fmaf(hv2.z, w2, acc2); acc2 = fmaf(hv2.w, w3, acc2);
        acc3 = fmaf(hv3.x, w0, acc3); acc3 = fmaf(hv3.y, w1, acc3);
        acc3 = fmaf(hv3.z, w2, acc3); acc3 = fmaf(hv3.w, w3, acc3);
    }
    o[(size_t)(g0 + 0) * D + col] = acc0;
    o[(size_t)(g0 + 1) * D + col] = acc1;
    o[(size_t)(g0 + 2) * D + col] = acc2;
    o[(size_t)(g0 + 3) * D + col] = acc3;
}

// ---------------- K_AGGMLP3: wave-specialized — waves 0-1 agg, waves 2-3 stage W1 -> LDS ----------------
// Separate vmcnt domains: stage waves' 64KB slab loads never block agg waves' gathers.
__global__ __launch_bounds__(256) void k_aggmlp3(const int* __restrict__ cnt,
                                                 const int* __restrict__ ssrc,
                                                 const float* __restrict__ xl,
                                                 const float* __restrict__ xr,
                                                 const float* __restrict__ att,
                                                 const float* __restrict__ bias,
                                                 const float* __restrict__ W1,
                                                 float* __restrict__ partials) {
    int wid = threadIdx.x >> 6;
    int lane = threadIdx.x & 63;
    int t = blockIdx.x;
    int lane2 = lane * 2;
    __shared__ float w1s[D * D];      // 64 KB slab
    __shared__ float2 red[4][64];
    __shared__ float zs[4];

    float2 acc = { 0.f, 0.f };
    float z = 0.f;

    if (wid >= 2) {
        // ---- stage waves: W1 rows (wid-2)*64 .. +63 into LDS (32 KB each) ----
        const float* gsrc = W1 + (size_t)t * D * D + (size_t)(wid - 2) * 64 * D + lane * 4;
        float* ldst = w1s + (wid - 2) * 64 * D + lane * 4;
#pragma unroll 4
        for (int i = 0; i < 32; ++i) {
            float4 v = *(const float4*)(gsrc + i * 256);
            *(float4*)(ldst + i * 256) = v;
        }
    } else {
        // ---- agg waves: butterfly body (round-8), wave w owns edge tile [w*64, w*64+64) ----
        float2 a  = *(const float2*)(att + lane2);
        float2 r2 = *(const float2*)(xr + (size_t)t * D + lane2);
        int deg = cnt[t]; if (deg > CAP) deg = CAP;    // self-loop => deg >= 1
        const int* srow = ssrc + t * CAP;
        int base = wid * 64;
        if (base < deg) {
            int nv = deg - base; if (nv > 64) nv = 64;
            int sv = srow[base + (lane < nv ? lane : nv - 1)];   // coalesced preload
            int e = 0;
            for (; e + 4 <= nv; e += 4) {
                int s0 = __shfl(sv, e), s1 = __shfl(sv, e + 1);
                int s2 = __shfl(sv, e + 2), s3 = __shfl(sv, e + 3);
                float2 l0 = *(const float2*)(xl + (size_t)s0 * D + lane2);
                float2 l1 = *(const float2*)(xl + (size_t)s1 * D + lane2);
                float2 l2 = *(const float2*)(xl + (size_t)s2 * D + lane2);
                float2 l3 = *(const float2*)(xl + (size_t)s3 * D + lane2);
                float v0 = leaky(l0.x + r2.x) * a.x + leaky(l0.y + r2.y) * a.y;
                float v1 = leaky(l1.x + r2.x) * a.x + leaky(l1.y + r2.y) * a.y;
                float v2 = leaky(l2.x + r2.x) * a.x + leaky(l2.y + r2.y) * a.y;
                float v3 = leaky(l3.x + r2.x) * a.x + leaky(l3.y + r2.y) * a.y;
#pragma unroll
                for (int off = 32; off; off >>= 1) {
                    v0 += __shfl_xor(v0, off);
                    v1 += __shfl_xor(v1, off);
                    v2 += __shfl_xor(v2, off);
                    v3 += __shfl_xor(v3, off);
                }
                float w0 = expf(v0), w1 = expf(v1), w2 = expf(v2), w3 = expf(v3);
                z += (w0 + w1) + (w2 + w3);
                acc.x = fmaf(w0, l0.x, acc.x); acc.y = fmaf(w0, l0.y, acc.y);
                acc.x = fmaf(w1, l1.x, acc.x); acc.y = fmaf(w1, l1.y, acc.y);
                acc.x = fmaf(w2, l2.x, acc.x); acc.y = fmaf(w2, l2.y, acc.y);
                acc.x = fmaf(w3, l3.x, acc.x); acc.y = fmaf(w3, l3.y, acc.y);
            }
            for (; e < nv; ++e) {
                int s = __shfl(sv, e);
                float2 l = *(const float2*)(xl + (size_t)s * D + lane2);
                float v = leaky(l.x + r2.x) * a.x + leaky(l.y + r2.y) * a.y;
#pragma unroll
                for (int off = 32; off; off >>= 1) v += __shfl_xor(v, off);
                float w = expf(v);
                z += w;
                acc.x = fmaf(w, l.x, acc.x);
                acc.y = fmaf(w, l.y, acc.y);
            }
        }
    }

    red[wid][lane] = acc;                // waves 2-3 contribute zeros
    if (lane == 0) zs[wid] = z;
    __syncthreads();                     // joins agg + stage (drains stage ds_writes)

    float2 s0 = red[0][lane], s1 = red[1][lane];
    float2 atot = { s0.x + s1.x, s0.y + s1.y };
    float zt = zs[0] + zs[1];
    float inv = 1.f / zt;
    float2 bv = *(const float2*)(bias + lane2);
    float2 o = { leaky(atot.x * inv + bv.x), leaky(atot.y * inv + bv.y) };   // f[t]

    // ---- GEMV from LDS: wave w covers rows w*32 .. w*32+31 ----
    const float* wrow = w1s + wid * 32 * D + lane2;
    float2 m = { 0.f, 0.f };
#pragma unroll
    for (int rp = 0; rp < 32; ++rp) {
        float fv = (rp & 1) ? __shfl(o.y, wid * 16 + (rp >> 1))
                            : __shfl(o.x, wid * 16 + (rp >> 1));
        float2 wv = *(const float2*)(wrow + (size_t)rp * D);
        m.x = fmaf(fv, wv.x, m.x);
        m.y = fmaf(fv, wv.y, m.y);
    }
    __syncthreads();                     // red reuse
    red[wid][lane] = m;
    __syncthreads();
    if (wid == 0) {
        float2 m0 = red[0][lane], m1 = red[1][lane], m2 = red[2][lane], m3 = red[3][lane];
        float2 s = { m0.x + m1.x + m2.x + m3.x, m0.y + m1.y + m2.y + m3.y };
        *(float2*)(partials + (size_t)t * D + lane2) = s;
    }
}

// ---------------- K6: 8-block column-sliced reduce + relu + dot W2 (rows = G) ----------------
__global__ __launch_bounds__(1024) void k_final8(const float* __restrict__ partials,
                                                 const float* __restrict__ b1,
                                                 const float* __restrict__ W2,
                                                 const float* __restrict__ b2,
                                                 float* __restrict__ out) {
    int tid = threadIdx.x;
    int rg = tid >> 4;
    int cl = tid & 15;
    int c = blockIdx.x * 16 + cl;
    float s = 0.f;
    for (int r = rg; r < G; r += 64) s += partials[(size_t)r * D + c];
    __shared__ float red[64][16];
    red[rg][cl] = s;
    __syncthreads();
    if (tid < 128) {
        int cc = tid & 15, seg = tid >> 4;
        float t2 = red[seg * 8][cc];
        for (int m = 1; m < 8; ++m) t2 += red[seg * 8 + m][cc];
        red[seg * 8][cc] = t2;
    }
    __syncthreads();
    if (tid < 16) {
        float tot = 0.f;
        for (int m = 0; m < 8; ++m) tot += red[m * 8][tid];
        float h1 = fmaxf(tot + b1[blockIdx.x * 16 + tid], 0.f);
        red[0][tid] = h1 * W2[blockIdx.x * 16 + tid];
    }
    __syncthreads();
    if (tid == 0) {
        float o = 0.f;
        for (int m = 0; m < 16; ++m) o += red[0][m];
        if (blockIdx.x == 0) o += b2[0];
        atomicAdd(out, o);
    }
}

extern "C" void kernel_launch(void* const* d_in, const int* in_sizes, int n_in,
                              void* d_out, int out_size, void* d_ws, size_t ws_size,
                              hipStream_t stream) {
    const float* x    = (const float*)d_in[0];
    const int*   ei   = (const int*)d_in[1];
    const float* Win  = (const float*)d_in[2];
    const float* bin  = (const float*)d_in[3];
    const float* Wl   = (const float*)d_in[4];
    const float* bl   = (const float*)d_in[5];
    const float* Wr   = (const float*)d_in[6];
    const float* br   = (const float*)d_in[7];
    const float* att  = (const float*)d_in[8];
    const float* bias = (const float*)d_in[9];
    const float* W1   = (const float*)d_in[10];
    const float* b1   = (const float*)d_in[11];
    const float* W2   = (const float*)d_in[12];
    const float* b2   = (const float*)d_in[13];
    float* out = (float*)d_out;

    float* ws       = (float*)d_ws;
    float* h        = ws;                 // GD
    float* xl       = h  + GD;            // GD
    float* xr       = xl + GD;            // GD
    float* partials = xr + GD;            // G*D
    int*   ssrc     = (int*)(partials + (size_t)GD);        // G*CAP
    int*   cnt      = ssrc + (size_t)G * CAP;               // G

    const int* srcA = ei;
    const int* dstA = ei + E;

    hipMemsetAsync(cnt, 0, G * sizeof(int), stream);
    k_fuseA<<<NB_PG + NB_H, 256, 0, stream>>>(x, Win, bin, h, srcA, dstA, cnt, ssrc, out);
    k_xlxr3<<<NB_X, 256, 0, stream>>>(h, Wl, bl, Wr, br, xl, xr);
    k_aggmlp3<<<G, 256, 0, stream>>>(cnt, ssrc, xl, xr, att, bias, W1, partials);
    k_final8<<<8, 1024, 0, stream>>>(partials, b1, W2, b2, out);
}

// Round 21
// 158.631 us; speedup vs baseline: 1.4374x; 1.4374x over previous
//
#include <hip/hip_runtime.h>
#include <math.h>

#define G 5000
#define IN 64
#define D 128
#define E 240000
#define EG (E + G)
#define SLOPE 0.2f
#define GD (G * D)
#define CAP 128          // fixed bucket capacity per destination (deg ~ Poisson(48)+1)
#define NB_PG 1250       // pergene blocks (4 genes each)
#define NB_H 240         // bucket blocks (61440 int4 units >= 61250)
#define NB_X 1250        // xlxr blocks (4 genes each)

__device__ __forceinline__ float leaky(float v) { return v >= 0.f ? v : SLOPE * v; }

// ---------------- K_A: pergene (round-2 exact body) + bucket (fixed-cap) ----------------
__global__ __launch_bounds__(256) void k_fuseA(const float* __restrict__ x,
                                               const float* __restrict__ Win,
                                               const float* __restrict__ bin,
                                               float* __restrict__ h,
                                               const int* __restrict__ srcA,
                                               const int* __restrict__ dstA,
                                               int* __restrict__ cnt,
                                               int* __restrict__ ssrc,
                                               float* __restrict__ outz) {
    if (blockIdx.x == 0 && threadIdx.x == 0) *outz = 0.f;   // consumed only by k_final8 (stream-ordered)
    if (blockIdx.x < NB_PG) {
        int g = (blockIdx.x * 256 + threadIdx.x) >> 6;
        int lane = threadIdx.x & 63;
        if (g >= G) return;
        float xv = x[g * IN + lane];
        const float* W = Win + (size_t)g * IN * D + lane * 2;
        float2 acc = *(const float2*)(bin + g * D + lane * 2);
#pragma unroll
        for (int i = 0; i < IN; ++i) {
            float xi = __shfl(xv, i);
            float2 w2 = *(const float2*)(W + (size_t)i * D);
            acc.x = fmaf(xi, w2.x, acc.x);
            acc.y = fmaf(xi, w2.y, acc.y);
        }
        float2 o = { fmaxf(acc.x, 0.f), fmaxf(acc.y, 0.f) };
        *(float2*)(h + g * D + lane * 2) = o;
    } else {
        int base = ((blockIdx.x - NB_PG) * 256 + threadIdx.x) * 4;
        if (base >= EG) return;
        if (base + 4 <= E) {
            int4 s4 = *(const int4*)(srcA + base);
            int4 d4 = *(const int4*)(dstA + base);
            int p;
            p = atomicAdd(&cnt[d4.x], 1); if (p < CAP) ssrc[d4.x * CAP + p] = s4.x;
            p = atomicAdd(&cnt[d4.y], 1); if (p < CAP) ssrc[d4.y * CAP + p] = s4.y;
            p = atomicAdd(&cnt[d4.z], 1); if (p < CAP) ssrc[d4.z * CAP + p] = s4.z;
            p = atomicAdd(&cnt[d4.w], 1); if (p < CAP) ssrc[d4.w * CAP + p] = s4.w;
        } else {
            for (int kk = 0; kk < 4; ++kk) {
                int i = base + kk;
                if (i < EG) {
                    int s, t;
                    if (i < E) { s = srcA[i]; t = dstA[i]; }
                    else { s = i - E; t = s; }
                    int p = atomicAdd(&cnt[t], 1);
                    if (p < CAP) ssrc[t * CAP + p] = s;
                }
            }
        }
    }
}

// ---------------- K_XLXR3: column-per-thread, 4 genes/block (round-16 exact) ----------------
__global__ __launch_bounds__(256) void k_xlxr3(const float* __restrict__ h,
                                               const float* __restrict__ Wl,
                                               const float* __restrict__ bl,
                                               const float* __restrict__ Wr,
                                               const float* __restrict__ br,
                                               float* __restrict__ xl,
                                               float* __restrict__ xr) {
    int g0 = blockIdx.x * 4;
    int tid = threadIdx.x;
    int half = tid >> 7;
    int col = tid & 127;
    const float* W = half ? Wr : Wl;
    const float* bb = half ? br : bl;
    float* o = half ? xr : xl;
    const float* h0p = h + (size_t)(g0 + 0) * D;
    const float* h1p = h + (size_t)(g0 + 1) * D;
    const float* h2p = h + (size_t)(g0 + 2) * D;
    const float* h3p = h + (size_t)(g0 + 3) * D;
    float b = bb[col];
    float acc0 = b, acc1 = b, acc2 = b, acc3 = b;
#pragma unroll 8
    for (int k4 = 0; k4 < 32; ++k4) {
        int k = k4 * 4;
        float4 hv0 = *(const float4*)(h0p + k);
        float4 hv1 = *(const float4*)(h1p + k);
        float4 hv2 = *(const float4*)(h2p + k);
        float4 hv3 = *(const float4*)(h3p + k);
        float w0 = W[(size_t)(k + 0) * D + col];
        float w1 = W[(size_t)(k + 1) * D + col];
        float w2 = W[(size_t)(k + 2) * D + col];
        float w3 = W[(size_t)(k + 3) * D + col];
        acc0 = fmaf(hv0.x, w0, acc0); acc0 = fmaf(hv0.y, w1, acc0);
        acc0 = fmaf(hv0.z, w2, acc0); acc0 = fmaf(hv0.w, w3, acc0);
        acc1 = fmaf(hv1.x, w0, acc1); acc1 = fmaf(hv1.y, w1, acc1);
        acc1 = fmaf(hv1.z, w2, acc1); acc1 = fmaf(hv1.w, w3, acc1);
        acc2 = fmaf(hv2.x, w0, acc2); acc2 = fmaf(hv2.y, w1, acc2);
        acc2 = fmaf(hv2.z, w2, acc2); acc2 = fmaf(hv2.w, w3, acc2);
        acc3 = fmaf(hv3.x, w0, acc3); acc3 = fmaf(hv3.y, w1, acc3);
        acc3 = fmaf(hv3.z, w2, acc3); acc3 = fmaf(hv3.w, w3, acc3);
    }
    o[(size_t)(g0 + 0) * D + col] = acc0;
    o[(size_t)(g0 + 1) * D + col] = acc1;
    o[(size_t)(g0 + 2) * D + col] = acc2;
    o[(size_t)(g0 + 3) * D + col] = acc3;
}

// ---------------- K_AGGMLP4: one dest/block, 4 waves split edges (32 each), GEMV from global ----------------
// No prefetch hacks; overlap comes from block-generation stagger (5000 blocks, ~5 gen/CU).
__global__ __launch_bounds__(256) void k_aggmlp4(const int* __restrict__ cnt,
                                                 const int* __restrict__ ssrc,
                                                 const float* __restrict__ xl,
                                                 const float* __restrict__ xr,
                                                 const float* __restrict__ att,
                                                 const float* __restrict__ bias,
                                                 const float* __restrict__ W1,
                                                 float* __restrict__ partials) {
    int wid = threadIdx.x >> 6;
    int lane = threadIdx.x & 63;
    int t = blockIdx.x;
    int lane2 = lane * 2;
    __shared__ float2 red[4][64];
    __shared__ float zs[4];

    // ---- agg: butterfly body (round-8, verified), wave w owns edge chunk [w*32, w*32+32) ----
    float2 a  = *(const float2*)(att + lane2);
    float2 r2 = *(const float2*)(xr + (size_t)t * D + lane2);
    int deg = cnt[t]; if (deg > CAP) deg = CAP;    // self-loop => deg >= 1
    const int* srow = ssrc + t * CAP;
    float2 acc = { 0.f, 0.f };
    float z = 0.f;
    int base = wid * 32;
    if (base < deg) {
        int nv = deg - base; if (nv > 32) nv = 32;
        int sv = srow[base + (lane < nv ? lane : nv - 1)];   // coalesced preload (clamped)
        int e = 0;
        for (; e + 4 <= nv; e += 4) {
            int s0 = __shfl(sv, e), s1 = __shfl(sv, e + 1);
            int s2 = __shfl(sv, e + 2), s3 = __shfl(sv, e + 3);
            float2 l0 = *(const float2*)(xl + (size_t)s0 * D + lane2);
            float2 l1 = *(const float2*)(xl + (size_t)s1 * D + lane2);
            float2 l2 = *(const float2*)(xl + (size_t)s2 * D + lane2);
            float2 l3 = *(const float2*)(xl + (size_t)s3 * D + lane2);
            float v0 = leaky(l0.x + r2.x) * a.x + leaky(l0.y + r2.y) * a.y;
            float v1 = leaky(l1.x + r2.x) * a.x + leaky(l1.y + r2.y) * a.y;
            float v2 = leaky(l2.x + r2.x) * a.x + leaky(l2.y + r2.y) * a.y;
            float v3 = leaky(l3.x + r2.x) * a.x + leaky(l3.y + r2.y) * a.y;
#pragma unroll
            for (int off = 32; off; off >>= 1) {
                v0 += __shfl_xor(v0, off);
                v1 += __shfl_xor(v1, off);
                v2 += __shfl_xor(v2, off);
                v3 += __shfl_xor(v3, off);
            }
            float w0 = expf(v0), w1 = expf(v1), w2 = expf(v2), w3 = expf(v3);
            z += (w0 + w1) + (w2 + w3);
            acc.x = fmaf(w0, l0.x, acc.x); acc.y = fmaf(w0, l0.y, acc.y);
            acc.x = fmaf(w1, l1.x, acc.x); acc.y = fmaf(w1, l1.y, acc.y);
            acc.x = fmaf(w2, l2.x, acc.x); acc.y = fmaf(w2, l2.y, acc.y);
            acc.x = fmaf(w3, l3.x, acc.x); acc.y = fmaf(w3, l3.y, acc.y);
        }
        for (; e < nv; ++e) {
            int s = __shfl(sv, e);
            float2 l = *(const float2*)(xl + (size_t)s * D + lane2);
            float v = leaky(l.x + r2.x) * a.x + leaky(l.y + r2.y) * a.y;
#pragma unroll
            for (int off = 32; off; off >>= 1) v += __shfl_xor(v, off);
            float w = expf(v);
            z += w;
            acc.x = fmaf(w, l.x, acc.x);
            acc.y = fmaf(w, l.y, acc.y);
        }
    }

    // ---- block reduce acc/z across 4 waves; every wave computes f[t] ----
    red[wid][lane] = acc;
    if (lane == 0) zs[wid] = z;      // z uniform per wave post-butterfly
    __syncthreads();
    float2 s0 = red[0][lane], s1 = red[1][lane], s2 = red[2][lane], s3 = red[3][lane];
    float2 atot = { s0.x + s1.x + s2.x + s3.x, s0.y + s1.y + s2.y + s3.y };
    float zt = zs[0] + zs[1] + zs[2] + zs[3];
    float inv = 1.f / zt;
    float2 bv = *(const float2*)(bias + lane2);
    float2 o = { leaky(atot.x * inv + bv.x), leaky(atot.y * inv + bv.y) };   // f[t]

    // ---- GEMV from global W1 (round-18 exact pattern): wave w covers rows w*32 .. w*32+31 ----
    const float* W1p = W1 + ((size_t)t * D + wid * 32) * D + lane2;
    float2 m = { 0.f, 0.f };
#pragma unroll
    for (int rp = 0; rp < 16; ++rp) {
        float fx = __shfl(o.x, wid * 16 + rp);     // f[wid*32 + 2*rp]
        float fy = __shfl(o.y, wid * 16 + rp);     // f[wid*32 + 2*rp + 1]
        float2 wa = *(const float2*)(W1p + (size_t)(2 * rp) * D);
        float2 wb = *(const float2*)(W1p + (size_t)(2 * rp + 1) * D);
        m.x = fmaf(fx, wa.x, m.x); m.y = fmaf(fx, wa.y, m.y);
        m.x = fmaf(fy, wb.x, m.x); m.y = fmaf(fy, wb.y, m.y);
    }
    __syncthreads();                 // red reuse
    red[wid][lane] = m;
    __syncthreads();
    if (wid == 0) {
        float2 m0 = red[0][lane], m1 = red[1][lane], m2 = red[2][lane], m3 = red[3][lane];
        float2 s = { m0.x + m1.x + m2.x + m3.x, m0.y + m1.y + m2.y + m3.y };
        *(float2*)(partials + (size_t)t * D + lane2) = s;
    }
}

// ---------------- K6: 8-block column-sliced reduce + relu + dot W2 (rows = G) ----------------
__global__ __launch_bounds__(1024) void k_final8(const float* __restrict__ partials,
                                                 const float* __restrict__ b1,
                                                 const float* __restrict__ W2,
                                                 const float* __restrict__ b2,
                                                 float* __restrict__ out) {
    int tid = threadIdx.x;
    int rg = tid >> 4;
    int cl = tid & 15;
    int c = blockIdx.x * 16 + cl;
    float s = 0.f;
    for (int r = rg; r < G; r += 64) s += partials[(size_t)r * D + c];
    __shared__ float red[64][16];
    red[rg][cl] = s;
    __syncthreads();
    if (tid < 128) {
        int cc = tid & 15, seg = tid >> 4;
        float t2 = red[seg * 8][cc];
        for (int m = 1; m < 8; ++m) t2 += red[seg * 8 + m][cc];
        red[seg * 8][cc] = t2;
    }
    __syncthreads();
    if (tid < 16) {
        float tot = 0.f;
        for (int m = 0; m < 8; ++m) tot += red[m * 8][tid];
        float h1 = fmaxf(tot + b1[blockIdx.x * 16 + tid], 0.f);
        red[0][tid] = h1 * W2[blockIdx.x * 16 + tid];
    }
    __syncthreads();
    if (tid == 0) {
        float o = 0.f;
        for (int m = 0; m < 16; ++m) o += red[0][m];
        if (blockIdx.x == 0) o += b2[0];
        atomicAdd(out, o);
    }
}

extern "C" void kernel_launch(void* const* d_in, const int* in_sizes, int n_in,
                              void* d_out, int out_size, void* d_ws, size_t ws_size,
                              hipStream_t stream) {
    const float* x    = (const float*)d_in[0];
    const int*   ei   = (const int*)d_in[1];
    const float* Win  = (const float*)d_in[2];
    const float* bin  = (const float*)d_in[3];
    const float* Wl   = (const float*)d_in[4];
    const float* bl   = (const float*)d_in[5];
    const float* Wr   = (const float*)d_in[6];
    const float* br   = (const float*)d_in[7];
    const float* att  = (const float*)d_in[8];
    const float* bias = (const float*)d_in[9];
    const float* W1   = (const float*)d_in[10];
    const float* b1   = (const float*)d_in[11];
    const float* W2   = (const float*)d_in[12];
    const float* b2   = (const float*)d_in[13];
    float* out = (float*)d_out;

    float* ws       = (float*)d_ws;
    float* h        = ws;                 // GD
    float* xl       = h  + GD;            // GD
    float* xr       = xl + GD;            // GD
    float* partials = xr + GD;            // G*D
    int*   ssrc     = (int*)(partials + (size_t)GD);        // G*CAP
    int*   cnt      = ssrc + (size_t)G * CAP;               // G

    const int* srcA = ei;
    const int* dstA = ei + E;

    hipMemsetAsync(cnt, 0, G * sizeof(int), stream);
    k_fuseA<<<NB_PG + NB_H, 256, 0, stream>>>(x, Win, bin, h, srcA, dstA, cnt, ssrc, out);
    k_xlxr3<<<NB_X, 256, 0, stream>>>(h, Wl, bl, Wr, br, xl, xr);
    k_aggmlp4<<<G, 256, 0, stream>>>(cnt, ssrc, xl, xr, att, bias, W1, partials);
    k_final8<<<8, 1024, 0, stream>>>(partials, b1, W2, b2, out);
}

// Round 22
// 157.474 us; speedup vs baseline: 1.4480x; 1.0074x over previous
//
#include <hip/hip_runtime.h>
#include <math.h>

#define G 5000
#define IN 64
#define D 128
#define E 240000
#define EG (E + G)
#define SLOPE 0.2f
#define GD (G * D)
#define CAP 128          // fixed bucket capacity per destination (deg ~ Poisson(48)+1)
#define HALF 2500        // dests pre-aggregated by k_agg (pipeline priming)
#define NB_M 1250        // aggmlp blocks (4 dests each)
#define NB_PG 1250       // pergene blocks (4 genes each)
#define NB_H 240         // bucket blocks (61440 int4 units >= 61250)
#define NB_X 1250        // xlxr blocks (4 genes each)

__device__ __forceinline__ float leaky(float v) { return v >= 0.f ? v : SLOPE * v; }

// ---------------- shared butterfly agg body (round-8, measured 27.7us for all G) ----------------
__device__ __forceinline__ float2 agg_butterfly(int t, int lane, int lane2,
                                                const int* __restrict__ cnt,
                                                const int* __restrict__ ssrc,
                                                const float* __restrict__ xl,
                                                const float* __restrict__ xr,
                                                const float* __restrict__ att,
                                                const float* __restrict__ bias) {
    float2 a  = *(const float2*)(att + lane2);
    float2 r2 = *(const float2*)(xr + (size_t)t * D + lane2);
    int deg = cnt[t]; if (deg > CAP) deg = CAP;    // self-loop => deg >= 1
    const int* srow = ssrc + t * CAP;
    float2 acc = { 0.f, 0.f };
    float z = 0.f;
    for (int base = 0; base < deg; base += 64) {
        int nv = deg - base; if (nv > 64) nv = 64;
        int sv = srow[base + (lane < nv ? lane : nv - 1)];   // coalesced preload
        int e = 0;
        for (; e + 4 <= nv; e += 4) {
            int s0 = __shfl(sv, e), s1 = __shfl(sv, e + 1);
            int s2 = __shfl(sv, e + 2), s3 = __shfl(sv, e + 3);
            float2 l0 = *(const float2*)(xl + (size_t)s0 * D + lane2);
            float2 l1 = *(const float2*)(xl + (size_t)s1 * D + lane2);
            float2 l2 = *(const float2*)(xl + (size_t)s2 * D + lane2);
            float2 l3 = *(const float2*)(xl + (size_t)s3 * D + lane2);
            float v0 = leaky(l0.x + r2.x) * a.x + leaky(l0.y + r2.y) * a.y;
            float v1 = leaky(l1.x + r2.x) * a.x + leaky(l1.y + r2.y) * a.y;
            float v2 = leaky(l2.x + r2.x) * a.x + leaky(l2.y + r2.y) * a.y;
            float v3 = leaky(l3.x + r2.x) * a.x + leaky(l3.y + r2.y) * a.y;
#pragma unroll
            for (int off = 32; off; off >>= 1) {
                v0 += __shfl_xor(v0, off);
                v1 += __shfl_xor(v1, off);
                v2 += __shfl_xor(v2, off);
                v3 += __shfl_xor(v3, off);
            }
            float w0 = expf(v0), w1 = expf(v1), w2 = expf(v2), w3 = expf(v3);
            z += (w0 + w1) + (w2 + w3);
            acc.x = fmaf(w0, l0.x, acc.x); acc.y = fmaf(w0, l0.y, acc.y);
            acc.x = fmaf(w1, l1.x, acc.x); acc.y = fmaf(w1, l1.y, acc.y);
            acc.x = fmaf(w2, l2.x, acc.x); acc.y = fmaf(w2, l2.y, acc.y);
            acc.x = fmaf(w3, l3.x, acc.x); acc.y = fmaf(w3, l3.y, acc.y);
        }
        for (; e < nv; ++e) {
            int s = __shfl(sv, e);
            float2 l = *(const float2*)(xl + (size_t)s * D + lane2);
            float v = leaky(l.x + r2.x) * a.x + leaky(l.y + r2.y) * a.y;
#pragma unroll
            for (int off = 32; off; off >>= 1) v += __shfl_xor(v, off);
            float w = expf(v);
            z += w;
            acc.x = fmaf(w, l.x, acc.x);
            acc.y = fmaf(w, l.y, acc.y);
        }
    }
    float inv = 1.f / z;       // z identical on all lanes (post-butterfly)
    float2 bv = *(const float2*)(bias + lane2);
    float2 o = { leaky(acc.x * inv + bv.x), leaky(acc.y * inv + bv.y) };   // f[t]
    return o;
}

// ---------------- K_A: pergene (round-2 exact body) + bucket (fixed-cap) ----------------
__global__ __launch_bounds__(256) void k_fuseA(const float* __restrict__ x,
                                               const float* __restrict__ Win,
                                               const float* __restrict__ bin,
                                               float* __restrict__ h,
                                               const int* __restrict__ srcA,
                                               const int* __restrict__ dstA,
                                               int* __restrict__ cnt,
                                               int* __restrict__ ssrc,
                                               float* __restrict__ outz) {
    if (blockIdx.x == 0 && threadIdx.x == 0) *outz = 0.f;   // consumed only by k_final8 (stream-ordered)
    if (blockIdx.x < NB_PG) {
        int g = (blockIdx.x * 256 + threadIdx.x) >> 6;
        int lane = threadIdx.x & 63;
        if (g >= G) return;
        float xv = x[g * IN + lane];
        const float* W = Win + (size_t)g * IN * D + lane * 2;
        float2 acc = *(const float2*)(bin + g * D + lane * 2);
#pragma unroll
        for (int i = 0; i < IN; ++i) {
            float xi = __shfl(xv, i);
            float2 w2 = *(const float2*)(W + (size_t)i * D);
            acc.x = fmaf(xi, w2.x, acc.x);
            acc.y = fmaf(xi, w2.y, acc.y);
        }
        float2 o = { fmaxf(acc.x, 0.f), fmaxf(acc.y, 0.f) };
        *(float2*)(h + g * D + lane * 2) = o;
    } else {
        int base = ((blockIdx.x - NB_PG) * 256 + threadIdx.x) * 4;
        if (base >= EG) return;
        if (base + 4 <= E) {
            int4 s4 = *(const int4*)(srcA + base);
            int4 d4 = *(const int4*)(dstA + base);
            int p;
            p = atomicAdd(&cnt[d4.x], 1); if (p < CAP) ssrc[d4.x * CAP + p] = s4.x;
            p = atomicAdd(&cnt[d4.y], 1); if (p < CAP) ssrc[d4.y * CAP + p] = s4.y;
            p = atomicAdd(&cnt[d4.z], 1); if (p < CAP) ssrc[d4.z * CAP + p] = s4.z;
            p = atomicAdd(&cnt[d4.w], 1); if (p < CAP) ssrc[d4.w * CAP + p] = s4.w;
        } else {
            for (int kk = 0; kk < 4; ++kk) {
                int i = base + kk;
                if (i < EG) {
                    int s, t;
                    if (i < E) { s = srcA[i]; t = dstA[i]; }
                    else { s = i - E; t = s; }
                    int p = atomicAdd(&cnt[t], 1);
                    if (p < CAP) ssrc[t * CAP + p] = s;
                }
            }
        }
    }
}

// ---------------- K_XLXR3: column-per-thread, 4 genes/block (round-16 exact) ----------------
__global__ __launch_bounds__(256) void k_xlxr3(const float* __restrict__ h,
                                               const float* __restrict__ Wl,
                                               const float* __restrict__ bl,
                                               const float* __restrict__ Wr,
                                               const float* __restrict__ br,
                                               float* __restrict__ xl,
                                               float* __restrict__ xr) {
    int g0 = blockIdx.x * 4;
    int tid = threadIdx.x;
    int half = tid >> 7;
    int col = tid & 127;
    const float* W = half ? Wr : Wl;
    const float* bb = half ? br : bl;
    float* o = half ? xr : xl;
    const float* h0p = h + (size_t)(g0 + 0) * D;
    const float* h1p = h + (size_t)(g0 + 1) * D;
    const float* h2p = h + (size_t)(g0 + 2) * D;
    const float* h3p = h + (size_t)(g0 + 3) * D;
    float b = bb[col];
    float acc0 = b, acc1 = b, acc2 = b, acc3 = b;
#pragma unroll 8
    for (int k4 = 0; k4 < 32; ++k4) {
        int k = k4 * 4;
        float4 hv0 = *(const float4*)(h0p + k);
        float4 hv1 = *(const float4*)(h1p + k);
        float4 hv2 = *(const float4*)(h2p + k);
        float4 hv3 = *(const float4*)(h3p + k);
        float w0 = W[(size_t)(k + 0) * D + col];
        float w1 = W[(size_t)(k + 1) * D + col];
        float w2 = W[(size_t)(k + 2) * D + col];
        float w3 = W[(size_t)(k + 3) * D + col];
        acc0 = fmaf(hv0.x, w0, acc0); acc0 = fmaf(hv0.y, w1, acc0);
        acc0 = fmaf(hv0.z, w2, acc0); acc0 = fmaf(hv0.w, w3, acc0);
        acc1 = fmaf(hv1.x, w0, acc1); acc1 = fmaf(hv1.y, w1, acc1);
        acc1 = fmaf(hv1.z, w2, acc1); acc1 = fmaf(hv1.w, w3, acc1);
        acc2 = fmaf(hv2.x, w0, acc2); acc2 = fmaf(hv2.y, w1, acc2);
        acc2 = fmaf(hv2.z, w2, acc2); acc2 = fmaf(hv2.w, w3, acc2);
        acc3 = fmaf(hv3.x, w0, acc3); acc3 = fmaf(hv3.y, w1, acc3);
        acc3 = fmaf(hv3.z, w2, acc3); acc3 = fmaf(hv3.w, w3, acc3);
    }
    o[(size_t)(g0 + 0) * D + col] = acc0;
    o[(size_t)(g0 + 1) * D + col] = acc1;
    o[(size_t)(g0 + 2) * D + col] = acc2;
    o[(size_t)(g0 + 3) * D + col] = acc3;
}

// ---------------- K_AGG: pre-aggregate dests [0, HALF) -> f (pipeline priming) ----------------
__global__ __launch_bounds__(256) void k_agg(const int* __restrict__ cnt,
                                             const int* __restrict__ ssrc,
                                             const float* __restrict__ xl,
                                             const float* __restrict__ xr,
                                             const float* __restrict__ att,
                                             const float* __restrict__ bias,
                                             float* __restrict__ f) {
    int t = (blockIdx.x * 256 + threadIdx.x) >> 6;
    int lane = threadIdx.x & 63;
    if (t >= HALF) return;
    float2 o = agg_butterfly(t, lane, lane * 2, cnt, ssrc, xl, xr, att, bias);
    *(float2*)(f + (size_t)t * D + lane * 2) = o;
}

// ---------------- K_AGGMLP5: round-18 aggmlp, but t < HALF loads f and streams immediately ----------------
__global__ __launch_bounds__(256) void k_aggmlp5(const int* __restrict__ cnt,
                                                 const int* __restrict__ ssrc,
                                                 const float* __restrict__ xl,
                                                 const float* __restrict__ xr,
                                                 const float* __restrict__ att,
                                                 const float* __restrict__ bias,
                                                 const float* __restrict__ f,
                                                 const float* __restrict__ W1,
                                                 float* __restrict__ partials) {
    int wid = threadIdx.x >> 6;
    int lane = threadIdx.x & 63;
    int t = __builtin_amdgcn_readfirstlane(blockIdx.x * 4 + wid);   // wave-uniform
    __shared__ float2 red[4][64];
    int lane2 = lane * 2;

    float2 o;
    if (t < HALF) {
        o = *(const float2*)(f + (size_t)t * D + lane2);   // primed -> stream W1 immediately
    } else {
        o = agg_butterfly(t, lane, lane2, cnt, ssrc, xl, xr, att, bias);
    }

    // ---- fused MLP1 slab: rows t*128 .. t*128+127 of W1, f_t broadcast from regs (round-18 exact) ----
    const float* W1p = W1 + (size_t)t * D * D + lane2;
    float2 m = { 0.f, 0.f };
#pragma unroll 8
    for (int dp = 0; dp < 64; ++dp) {
        float fx = __shfl(o.x, dp);
        float fy = __shfl(o.y, dp);
        float2 wa = *(const float2*)(W1p + (size_t)(2 * dp) * D);
        float2 wb = *(const float2*)(W1p + (size_t)(2 * dp + 1) * D);
        m.x = fmaf(fx, wa.x, m.x); m.y = fmaf(fx, wa.y, m.y);
        m.x = fmaf(fy, wb.x, m.x); m.y = fmaf(fy, wb.y, m.y);
    }
    red[wid][lane] = m;
    __syncthreads();
    if (wid == 0) {
        float2 s0 = red[0][lane], s1 = red[1][lane], s2 = red[2][lane], s3 = red[3][lane];
        float2 s = { s0.x + s1.x + s2.x + s3.x, s0.y + s1.y + s2.y + s3.y };
        *(float2*)(partials + (size_t)blockIdx.x * D + lane2) = s;
    }
}

// ---------------- K6: 8-block column-sliced reduce + relu + dot W2 (rows = NB_M) ----------------
__global__ __launch_bounds__(1024) void k_final8(const float* __restrict__ partials,
                                                 const float* __restrict__ b1,
                                                 const float* __restrict__ W2,
                                                 const float* __restrict__ b2,
                                                 float* __restrict__ out) {
    int tid = threadIdx.x;
    int rg = tid >> 4;
    int cl = tid & 15;
    int c = blockIdx.x * 16 + cl;
    float s = 0.f;
    for (int r = rg; r < NB_M; r += 64) s += partials[(size_t)r * D + c];
    __shared__ float red[64][16];
    red[rg][cl] = s;
    __syncthreads();
    if (tid < 128) {
        int cc = tid & 15, seg = tid >> 4;
        float t2 = red[seg * 8][cc];
        for (int m = 1; m < 8; ++m) t2 += red[seg * 8 + m][cc];
        red[seg * 8][cc] = t2;
    }
    __syncthreads();
    if (tid < 16) {
        float tot = 0.f;
        for (int m = 0; m < 8; ++m) tot += red[m * 8][tid];
        float h1 = fmaxf(tot + b1[blockIdx.x * 16 + tid], 0.f);
        red[0][tid] = h1 * W2[blockIdx.x * 16 + tid];
    }
    __syncthreads();
    if (tid == 0) {
        float o = 0.f;
        for (int m = 0; m < 16; ++m) o += red[0][m];
        if (blockIdx.x == 0) o += b2[0];
        atomicAdd(out, o);
    }
}

extern "C" void kernel_launch(void* const* d_in, const int* in_sizes, int n_in,
                              void* d_out, int out_size, void* d_ws, size_t ws_size,
                              hipStream_t stream) {
    const float* x    = (const float*)d_in[0];
    const int*   ei   = (const int*)d_in[1];
    const float* Win  = (const float*)d_in[2];
    const float* bin  = (const float*)d_in[3];
    const float* Wl   = (const float*)d_in[4];
    const float* bl   = (const float*)d_in[5];
    const float* Wr   = (const float*)d_in[6];
    const float* br   = (const float*)d_in[7];
    const float* att  = (const float*)d_in[8];
    const float* bias = (const float*)d_in[9];
    const float* W1   = (const float*)d_in[10];
    const float* b1   = (const float*)d_in[11];
    const float* W2   = (const float*)d_in[12];
    const float* b2   = (const float*)d_in[13];
    float* out = (float*)d_out;

    float* ws       = (float*)d_ws;
    float* h        = ws;                 // GD
    float* xl       = h  + GD;            // GD
    float* xr       = xl + GD;            // GD
    float* f        = xr + GD;            // GD (only [0,HALF) rows used)
    float* partials = f  + GD;            // NB_M*D
    int*   ssrc     = (int*)(partials + (size_t)NB_M * D);  // G*CAP
    int*   cnt      = ssrc + (size_t)G * CAP;               // G

    const int* srcA = ei;
    const int* dstA = ei + E;

    hipMemsetAsync(cnt, 0, G * sizeof(int), stream);
    k_fuseA<<<NB_PG + NB_H, 256, 0, stream>>>(x, Win, bin, h, srcA, dstA, cnt, ssrc, out);
    k_xlxr3<<<NB_X, 256, 0, stream>>>(h, Wl, bl, Wr, br, xl, xr);
    k_agg<<<(HALF * 64) / 256, 256, 0, stream>>>(cnt, ssrc, xl, xr, att, bias, f);
    k_aggmlp5<<<NB_M, 256, 0, stream>>>(cnt, ssrc, xl, xr, att, bias, f, W1, partials);
    k_final8<<<8, 1024, 0, stream>>>(partials, b1, W2, b2, out);
}

// Round 23
// 139.367 us; speedup vs baseline: 1.6361x; 1.1299x over previous
//
#include <hip/hip_runtime.h>
#include <math.h>

#define G 5000
#define IN 64
#define D 128
#define E 240000
#define EG (E + G)
#define SLOPE 0.2f
#define GD (G * D)
#define CAP 128          // fixed bucket capacity per destination (deg ~ Poisson(48)+1)
#define NB_M 1250        // aggmlp blocks (4 dests each)
#define NB_PG 1250       // pergene blocks (4 genes each)
#define NB_H 240         // bucket blocks (61440 int4 units >= 61250)
#define NB_X 1250        // xlxr blocks (4 genes each)

__device__ __forceinline__ float leaky(float v) { return v >= 0.f ? v : SLOPE * v; }

// ---------------- K_A: pergene (round-2 exact body) + bucket (fixed-cap) ----------------
__global__ __launch_bounds__(256) void k_fuseA(const float* __restrict__ x,
                                               const float* __restrict__ Win,
                                               const float* __restrict__ bin,
                                               float* __restrict__ h,
                                               const int* __restrict__ srcA,
                                               const int* __restrict__ dstA,
                                               int* __restrict__ cnt,
                                               int* __restrict__ ssrc,
                                               float* __restrict__ outz) {
    if (blockIdx.x == 0 && threadIdx.x == 0) *outz = 0.f;   // consumed only by k_final8 (stream-ordered)
    if (blockIdx.x < NB_PG) {
        int g = (blockIdx.x * 256 + threadIdx.x) >> 6;
        int lane = threadIdx.x & 63;
        if (g >= G) return;
        float xv = x[g * IN + lane];
        const float* W = Win + (size_t)g * IN * D + lane * 2;
        float2 acc = *(const float2*)(bin + g * D + lane * 2);
#pragma unroll
        for (int i = 0; i < IN; ++i) {
            float xi = __shfl(xv, i);
            float2 w2 = *(const float2*)(W + (size_t)i * D);
            acc.x = fmaf(xi, w2.x, acc.x);
            acc.y = fmaf(xi, w2.y, acc.y);
        }
        float2 o = { fmaxf(acc.x, 0.f), fmaxf(acc.y, 0.f) };
        *(float2*)(h + g * D + lane * 2) = o;
    } else {
        int base = ((blockIdx.x - NB_PG) * 256 + threadIdx.x) * 4;
        if (base >= EG) return;
        if (base + 4 <= E) {
            int4 s4 = *(const int4*)(srcA + base);
            int4 d4 = *(const int4*)(dstA + base);
            int p;
            p = atomicAdd(&cnt[d4.x], 1); if (p < CAP) ssrc[d4.x * CAP + p] = s4.x;
            p = atomicAdd(&cnt[d4.y], 1); if (p < CAP) ssrc[d4.y * CAP + p] = s4.y;
            p = atomicAdd(&cnt[d4.z], 1); if (p < CAP) ssrc[d4.z * CAP + p] = s4.z;
            p = atomicAdd(&cnt[d4.w], 1); if (p < CAP) ssrc[d4.w * CAP + p] = s4.w;
        } else {
            for (int kk = 0; kk < 4; ++kk) {
                int i = base + kk;
                if (i < EG) {
                    int s, t;
                    if (i < E) { s = srcA[i]; t = dstA[i]; }
                    else { s = i - E; t = s; }
                    int p = atomicAdd(&cnt[t], 1);
                    if (p < CAP) ssrc[t * CAP + p] = s;
                }
            }
        }
    }
}

// ---------------- K_XLXR3: column-per-thread, 4 genes/block (round-16 exact) ----------------
__global__ __launch_bounds__(256) void k_xlxr3(const float* __restrict__ h,
                                               const float* __restrict__ Wl,
                                               const float* __restrict__ bl,
                                               const float* __restrict__ Wr,
                                               const float* __restrict__ br,
                                               float* __restrict__ xl,
                                               float* __restrict__ xr) {
    int g0 = blockIdx.x * 4;
    int tid = threadIdx.x;
    int half = tid >> 7;
    int col = tid & 127;
    const float* W = half ? Wr : Wl;
    const float* bb = half ? br : bl;
    float* o = half ? xr : xl;
    const float* h0p = h + (size_t)(g0 + 0) * D;
    const float* h1p = h + (size_t)(g0 + 1) * D;
    const float* h2p = h + (size_t)(g0 + 2) * D;
    const float* h3p = h + (size_t)(g0 + 3) * D;
    float b = bb[col];
    float acc0 = b, acc1 = b, acc2 = b, acc3 = b;
#pragma unroll 8
    for (int k4 = 0; k4 < 32; ++k4) {
        int k = k4 * 4;
        float4 hv0 = *(const float4*)(h0p + k);
        float4 hv1 = *(const float4*)(h1p + k);
        float4 hv2 = *(const float4*)(h2p + k);
        float4 hv3 = *(const float4*)(h3p + k);
        float w0 = W[(size_t)(k + 0) * D + col];
        float w1 = W[(size_t)(k + 1) * D + col];
        float w2 = W[(size_t)(k + 2) * D + col];
        float w3 = W[(size_t)(k + 3) * D + col];
        acc0 = fmaf(hv0.x, w0, acc0); acc0 = fmaf(hv0.y, w1, acc0);
        acc0 = fmaf(hv0.z, w2, acc0); acc0 = fmaf(hv0.w, w3, acc0);
        acc1 = fmaf(hv1.x, w0, acc1); acc1 = fmaf(hv1.y, w1, acc1);
        acc1 = fmaf(hv1.z, w2, acc1); acc1 = fmaf(hv1.w, w3, acc1);
        acc2 = fmaf(hv2.x, w0, acc2); acc2 = fmaf(hv2.y, w1, acc2);
        acc2 = fmaf(hv2.z, w2, acc2); acc2 = fmaf(hv2.w, w3, acc2);
        acc3 = fmaf(hv3.x, w0, acc3); acc3 = fmaf(hv3.y, w1, acc3);
        acc3 = fmaf(hv3.z, w2, acc3); acc3 = fmaf(hv3.w, w3, acc3);
    }
    o[(size_t)(g0 + 0) * D + col] = acc0;
    o[(size_t)(g0 + 1) * D + col] = acc1;
    o[(size_t)(g0 + 2) * D + col] = acc2;
    o[(size_t)(g0 + 3) * D + col] = acc3;
}

// ---------------- K_AGGMLP: butterfly agg with 8-edge ILP + W1 GEMV slab (round-18 otherwise) ----------------
__global__ __launch_bounds__(256) void k_aggmlp(const int* __restrict__ cnt,
                                                const int* __restrict__ ssrc,
                                                const float* __restrict__ xl,
                                                const float* __restrict__ xr,
                                                const float* __restrict__ att,
                                                const float* __restrict__ bias,
                                                const float* __restrict__ W1,
                                                float* __restrict__ partials) {
    int wid = threadIdx.x >> 6;
    int lane = threadIdx.x & 63;
    int t = __builtin_amdgcn_readfirstlane(blockIdx.x * 4 + wid);   // wave-uniform
    __shared__ float2 red[4][64];
    int lane2 = lane * 2;
    float2 a  = *(const float2*)(att + lane2);
    float2 r2 = *(const float2*)(xr + (size_t)t * D + lane2);
    int deg = cnt[t]; if (deg > CAP) deg = CAP;    // self-loop => deg >= 1
    const int* srow = ssrc + t * CAP;
    float2 acc = { 0.f, 0.f };
    float z = 0.f;
    for (int base = 0; base < deg; base += 64) {
        int nv = deg - base; if (nv > 64) nv = 64;
        int sv = srow[base + (lane < nv ? lane : nv - 1)];   // coalesced preload
        int e = 0;
        // ---- 8 edges per group: 8 gathers in flight, 8 interleaved butterfly chains ----
        for (; e + 8 <= nv; e += 8) {
            int sA = __shfl(sv, e),     sB = __shfl(sv, e + 1);
            int sC = __shfl(sv, e + 2), sD = __shfl(sv, e + 3);
            int sE = __shfl(sv, e + 4), sF = __shfl(sv, e + 5);
            int sG = __shfl(sv, e + 6), sH = __shfl(sv, e + 7);
            float2 lA = *(const float2*)(xl + (size_t)sA * D + lane2);
            float2 lB = *(const float2*)(xl + (size_t)sB * D + lane2);
            float2 lC = *(const float2*)(xl + (size_t)sC * D + lane2);
            float2 lD = *(const float2*)(xl + (size_t)sD * D + lane2);
            float2 lE = *(const float2*)(xl + (size_t)sE * D + lane2);
            float2 lF = *(const float2*)(xl + (size_t)sF * D + lane2);
            float2 lG = *(const float2*)(xl + (size_t)sG * D + lane2);
            float2 lH = *(const float2*)(xl + (size_t)sH * D + lane2);
            float vA = leaky(lA.x + r2.x) * a.x + leaky(lA.y + r2.y) * a.y;
            float vB = leaky(lB.x + r2.x) * a.x + leaky(lB.y + r2.y) * a.y;
            float vC = leaky(lC.x + r2.x) * a.x + leaky(lC.y + r2.y) * a.y;
            float vD = leaky(lD.x + r2.x) * a.x + leaky(lD.y + r2.y) * a.y;
            float vE = leaky(lE.x + r2.x) * a.x + leaky(lE.y + r2.y) * a.y;
            float vF = leaky(lF.x + r2.x) * a.x + leaky(lF.y + r2.y) * a.y;
            float vG = leaky(lG.x + r2.x) * a.x + leaky(lG.y + r2.y) * a.y;
            float vH = leaky(lH.x + r2.x) * a.x + leaky(lH.y + r2.y) * a.y;
#pragma unroll
            for (int off = 32; off; off >>= 1) {
                vA += __shfl_xor(vA, off); vB += __shfl_xor(vB, off);
                vC += __shfl_xor(vC, off); vD += __shfl_xor(vD, off);
                vE += __shfl_xor(vE, off); vF += __shfl_xor(vF, off);
                vG += __shfl_xor(vG, off); vH += __shfl_xor(vH, off);
            }
            float wA = expf(vA), wB = expf(vB), wC = expf(vC), wD = expf(vD);
            float wE = expf(vE), wF = expf(vF), wG = expf(vG), wH = expf(vH);
            z += ((wA + wB) + (wC + wD)) + ((wE + wF) + (wG + wH));
            acc.x = fmaf(wA, lA.x, acc.x); acc.y = fmaf(wA, lA.y, acc.y);
            acc.x = fmaf(wB, lB.x, acc.x); acc.y = fmaf(wB, lB.y, acc.y);
            acc.x = fmaf(wC, lC.x, acc.x); acc.y = fmaf(wC, lC.y, acc.y);
            acc.x = fmaf(wD, lD.x, acc.x); acc.y = fmaf(wD, lD.y, acc.y);
            acc.x = fmaf(wE, lE.x, acc.x); acc.y = fmaf(wE, lE.y, acc.y);
            acc.x = fmaf(wF, lF.x, acc.x); acc.y = fmaf(wF, lF.y, acc.y);
            acc.x = fmaf(wG, lG.x, acc.x); acc.y = fmaf(wG, lG.y, acc.y);
            acc.x = fmaf(wH, lH.x, acc.x); acc.y = fmaf(wH, lH.y, acc.y);
        }
        for (; e + 4 <= nv; e += 4) {
            int s0 = __shfl(sv, e), s1 = __shfl(sv, e + 1);
            int s2 = __shfl(sv, e + 2), s3 = __shfl(sv, e + 3);
            float2 l0 = *(const float2*)(xl + (size_t)s0 * D + lane2);
            float2 l1 = *(const float2*)(xl + (size_t)s1 * D + lane2);
            float2 l2 = *(const float2*)(xl + (size_t)s2 * D + lane2);
            float2 l3 = *(const float2*)(xl + (size_t)s3 * D + lane2);
            float v0 = leaky(l0.x + r2.x) * a.x + leaky(l0.y + r2.y) * a.y;
            float v1 = leaky(l1.x + r2.x) * a.x + leaky(l1.y + r2.y) * a.y;
            float v2 = leaky(l2.x + r2.x) * a.x + leaky(l2.y + r2.y) * a.y;
            float v3 = leaky(l3.x + r2.x) * a.x + leaky(l3.y + r2.y) * a.y;
#pragma unroll
            for (int off = 32; off; off >>= 1) {
                v0 += __shfl_xor(v0, off);
                v1 += __shfl_xor(v1, off);
                v2 += __shfl_xor(v2, off);
                v3 += __shfl_xor(v3, off);
            }
            float w0 = expf(v0), w1 = expf(v1), w2 = expf(v2), w3 = expf(v3);
            z += (w0 + w1) + (w2 + w3);
            acc.x = fmaf(w0, l0.x, acc.x); acc.y = fmaf(w0, l0.y, acc.y);
            acc.x = fmaf(w1, l1.x, acc.x); acc.y = fmaf(w1, l1.y, acc.y);
            acc.x = fmaf(w2, l2.x, acc.x); acc.y = fmaf(w2, l2.y, acc.y);
            acc.x = fmaf(w3, l3.x, acc.x); acc.y = fmaf(w3, l3.y, acc.y);
        }
        for (; e < nv; ++e) {
            int s = __shfl(sv, e);
            float2 l = *(const float2*)(xl + (size_t)s * D + lane2);
            float v = leaky(l.x + r2.x) * a.x + leaky(l.y + r2.y) * a.y;
#pragma unroll
            for (int off = 32; off; off >>= 1) v += __shfl_xor(v, off);
            float w = expf(v);
            z += w;
            acc.x = fmaf(w, l.x, acc.x);
            acc.y = fmaf(w, l.y, acc.y);
        }
    }
    float inv = 1.f / z;       // z identical on all lanes (post-butterfly)
    float2 bv = *(const float2*)(bias + lane2);
    float2 o = { leaky(acc.x * inv + bv.x), leaky(acc.y * inv + bv.y) };   // f[t]

    // ---- fused MLP1 slab: rows t*128 .. t*128+127 of W1, f_t broadcast from regs (round-18 exact) ----
    const float* W1p = W1 + (size_t)t * D * D + lane2;
    float2 m = { 0.f, 0.f };
#pragma unroll 8
    for (int dp = 0; dp < 64; ++dp) {
        float fx = __shfl(o.x, dp);
        float fy = __shfl(o.y, dp);
        float2 wa = *(const float2*)(W1p + (size_t)(2 * dp) * D);
        float2 wb = *(const float2*)(W1p + (size_t)(2 * dp + 1) * D);
        m.x = fmaf(fx, wa.x, m.x); m.y = fmaf(fx, wa.y, m.y);
        m.x = fmaf(fy, wb.x, m.x); m.y = fmaf(fy, wb.y, m.y);
    }
    red[wid][lane] = m;
    __syncthreads();
    if (wid == 0) {
        float2 s0 = red[0][lane], s1 = red[1][lane], s2 = red[2][lane], s3 = red[3][lane];
        float2 s = { s0.x + s1.x + s2.x + s3.x, s0.y + s1.y + s2.y + s3.y };
        *(float2*)(partials + (size_t)blockIdx.x * D + lane2) = s;
    }
}

// ---------------- K6: 8-block column-sliced reduce + relu + dot W2 (round-10 exact) ----------------
__global__ __launch_bounds__(1024) void k_final8(const float* __restrict__ partials,
                                                 const float* __restrict__ b1,
                                                 const float* __restrict__ W2,
                                                 const float* __restrict__ b2,
                                                 float* __restrict__ out) {
    int tid = threadIdx.x;
    int rg = tid >> 4;
    int cl = tid & 15;
    int c = blockIdx.x * 16 + cl;
    float s = 0.f;
    for (int r = rg; r < NB_M; r += 64) s += partials[(size_t)r * D + c];
    __shared__ float red[64][16];
    red[rg][cl] = s;
    __syncthreads();
    if (tid < 128) {
        int cc = tid & 15, seg = tid >> 4;
        float t2 = red[seg * 8][cc];
        for (int m = 1; m < 8; ++m) t2 += red[seg * 8 + m][cc];
        red[seg * 8][cc] = t2;
    }
    __syncthreads();
    if (tid < 16) {
        float tot = 0.f;
        for (int m = 0; m < 8; ++m) tot += red[m * 8][tid];
        float h1 = fmaxf(tot + b1[blockIdx.x * 16 + tid], 0.f);
        red[0][tid] = h1 * W2[blockIdx.x * 16 + tid];
    }
    __syncthreads();
    if (tid == 0) {
        float o = 0.f;
        for (int m = 0; m < 16; ++m) o += red[0][m];
        if (blockIdx.x == 0) o += b2[0];
        atomicAdd(out, o);
    }
}

extern "C" void kernel_launch(void* const* d_in, const int* in_sizes, int n_in,
                              void* d_out, int out_size, void* d_ws, size_t ws_size,
                              hipStream_t stream) {
    const float* x    = (const float*)d_in[0];
    const int*   ei   = (const int*)d_in[1];
    const float* Win  = (const float*)d_in[2];
    const float* bin  = (const float*)d_in[3];
    const float* Wl   = (const float*)d_in[4];
    const float* bl   = (const float*)d_in[5];
    const float* Wr   = (const float*)d_in[6];
    const float* br   = (const float*)d_in[7];
    const float* att  = (const float*)d_in[8];
    const float* bias = (const float*)d_in[9];
    const float* W1   = (const float*)d_in[10];
    const float* b1   = (const float*)d_in[11];
    const float* W2   = (const float*)d_in[12];
    const float* b2   = (const float*)d_in[13];
    float* out = (float*)d_out;

    float* ws       = (float*)d_ws;
    float* h        = ws;                 // GD
    float* xl       = h  + GD;            // GD
    float* xr       = xl + GD;            // GD
    float* partials = xr + GD;            // NB_M*D
    int*   ssrc     = (int*)(partials + (size_t)NB_M * D);  // G*CAP
    int*   cnt      = ssrc + (size_t)G * CAP;               // G

    const int* srcA = ei;
    const int* dstA = ei + E;

    hipMemsetAsync(cnt, 0, G * sizeof(int), stream);
    k_fuseA<<<NB_PG + NB_H, 256, 0, stream>>>(x, Win, bin, h, srcA, dstA, cnt, ssrc, out);
    k_xlxr3<<<NB_X, 256, 0, stream>>>(h, Wl, bl, Wr, br, xl, xr);
    k_aggmlp<<<NB_M, 256, 0, stream>>>(cnt, ssrc, xl, xr, att, bias, W1, partials);
    k_final8<<<8, 1024, 0, stream>>>(partials, b1, W2, b2, out);
}